// Round 18
// baseline (1184.215 us; speedup 1.0000x reference)
//
#include <hip/hip_runtime.h>
#include <hip/hip_bf16.h>
#include <math.h>

#define D_MODEL 512
#define N_HEADS 8
#define HEAD 64
#define D_FF   2048
#define N_LAYERS 4
#define VOCAB  32000
#define BATCH  2
#define SEQ    1024

typedef __attribute__((ext_vector_type(8))) short bf16x8;
typedef __attribute__((ext_vector_type(4))) float f32x4;

__device__ __forceinline__ float b2f(short s) {
    unsigned int u = ((unsigned int)(unsigned short)s) << 16;
    float f; __builtin_memcpy(&f, &u, 4);
    return f;
}
__device__ __forceinline__ short f2b(float f) {
    __hip_bfloat16 h = __float2bfloat16(f);
    unsigned short u; __builtin_memcpy(&u, &h, 2);
    return (short)u;
}
__device__ __forceinline__ void storev(float* p, float v) { *p = v; }
__device__ __forceinline__ void storev(short* p, float v) { *p = f2b(v); }

// -------------------- tiled transpose+convert: src f32 [K][N] -> dst bf16 [N][K] -----
__device__ __forceinline__ void transT_tile(const float* __restrict__ s,
                                            short* __restrict__ d,
                                            int K, int N, int tx, int ty, int tid) {
    __shared__ float t[64][65];
    int r = tid >> 2, c4 = (tid & 3) * 4;
#pragma unroll
    for (int jj = 0; jj < 4; ++jj) {
        int col = c4 + jj * 16;
        *(float4*)&t[r][col] = *(const float4*)(s + (size_t)(ty * 64 + r) * N + tx * 64 + col);
    }
    __syncthreads();
#pragma unroll
    for (int jj = 0; jj < 4; ++jj) {
        int kc = c4 + jj * 16;
        short4 o = make_short4(f2b(t[kc][r]), f2b(t[kc + 1][r]),
                               f2b(t[kc + 2][r]), f2b(t[kc + 3][r]));
        *(short4*)(d + (size_t)(tx * 64 + r) * K + ty * 64 + kc) = o;
    }
}

__global__ __launch_bounds__(256) void transT_kernel(const float* __restrict__ src,
                                                     short* __restrict__ dst,
                                                     int K, int N) {
    const float* s = src + (size_t)blockIdx.z * K * N;
    short* d = dst + (size_t)blockIdx.z * K * N;
    transT_tile(s, d, K, N, blockIdx.x, blockIdx.y, threadIdx.x);
}

__global__ __launch_bounds__(256) void repack_attT_kernel(const float* __restrict__ encw,
                                                          const float* __restrict__ decw,
                                                          short* __restrict__ w_enc_qkv,
                                                          short* __restrict__ w_dec_qkv,
                                                          short* __restrict__ w_dec_kv,
                                                          short* __restrict__ w_o) {
    int z = blockIdx.y;
    const float* s; short* d;
    if (z < 12)      { int i = z / 3, j = z % 3;
                       s = encw + (size_t)(i * 4 + j) * 262144;
                       d = w_enc_qkv + (size_t)i * 786432 + j * 262144; }
    else if (z < 24) { int u = z - 12, i = u / 3, j = u % 3;
                       s = decw + (size_t)(i * 8 + j) * 262144;
                       d = w_dec_qkv + (size_t)i * 786432 + j * 262144; }
    else if (z < 32) { int u = z - 24, i = u / 2, j = u % 2;
                       s = decw + (size_t)(i * 8 + 5 + j) * 262144;
                       d = w_dec_kv + (size_t)i * 524288 + j * 262144; }
    else             { int u = z - 32; const float* b; int mi;
                       if (u < 4)       { b = encw; mi = u * 4 + 3; }
                       else if (u < 8)  { b = decw; mi = (u - 4) * 8 + 3; }
                       else if (u < 12) { b = decw; mi = (u - 8) * 8 + 4; }
                       else             { b = decw; mi = (u - 12) * 8 + 7; }
                       s = b + (size_t)mi * 262144; d = w_o + (size_t)u * 262144; }
    int bx = blockIdx.x;
    transT_tile(s, d, 512, 512, bx & 7, bx >> 3, threadIdx.x);
}

// -------------------- embedding + posenc, both streams in one launch ----------------
__global__ void embed_kernel(const int* __restrict__ tokA, const int* __restrict__ tokB,
                             const float* __restrict__ embA, const float* __restrict__ embB,
                             float* __restrict__ outA, float* __restrict__ outB) {
    int row = blockIdx.x;
    const int* tok = blockIdx.y ? tokB : tokA;
    const float* emb = blockIdx.y ? embB : embA;
    float* out = blockIdx.y ? outB : outA;
    int s = row % SEQ;
    int token = tok[row];
    const float scale = 22.627416997969522f;
    const float c = -1.7988945941359737e-2f;
    for (int d = threadIdx.x; d < D_MODEL; d += blockDim.x) {
        int i2 = (d >> 1) * 2;
        float div = expf((float)i2 * c);
        float ang = (float)s * div;
        float pe = (d & 1) ? cosf(ang) : sinf(ang);
        out[(size_t)row * D_MODEL + d] = emb[(size_t)token * D_MODEL + d] * scale + pe;
    }
}

// -------------------- layernorm: wave-per-row, 4 rows/block --------------------
__global__ __launch_bounds__(256) void ln_kernel(const float* __restrict__ x,
                                                 const float* __restrict__ g,
                                                 const float* __restrict__ b,
                                                 short* __restrict__ out) {
    int row = blockIdx.x * 4 + (threadIdx.x >> 6);
    int lane = threadIdx.x & 63;
    const float4* xr = (const float4*)(x + (size_t)row * D_MODEL);
    float4 v0 = xr[lane * 2], v1 = xr[lane * 2 + 1];
    float c[8] = { v0.x, v0.y, v0.z, v0.w, v1.x, v1.y, v1.z, v1.w };
    float s = ((c[0] + c[1]) + (c[2] + c[3])) + ((c[4] + c[5]) + (c[6] + c[7]));
#pragma unroll
    for (int off = 1; off < 64; off <<= 1) s += __shfl_xor(s, off);
    float mean = s * (1.0f / 512.0f);
    float q = 0.0f;
#pragma unroll
    for (int j = 0; j < 8; ++j) { c[j] -= mean; q += c[j] * c[j]; }
#pragma unroll
    for (int off = 1; off < 64; off <<= 1) q += __shfl_xor(q, off);
    float inv = 1.0f / sqrtf(q * (1.0f / 511.0f) + 1e-6f);
    const float4* gp = (const float4*)g;
    const float4* bp = (const float4*)b;
    float4 g0 = gp[lane * 2], g1 = gp[lane * 2 + 1];
    float4 b0 = bp[lane * 2], b1 = bp[lane * 2 + 1];
    float gg[8] = { g0.x, g0.y, g0.z, g0.w, g1.x, g1.y, g1.z, g1.w };
    float bb[8] = { b0.x, b0.y, b0.z, b0.w, b1.x, b1.y, b1.z, b1.w };
    bf16x8 res;
#pragma unroll
    for (int j = 0; j < 8; ++j) res[j] = f2b(gg[j] * (c[j] * inv) + bb[j]);
    *(bf16x8*)(out + (size_t)row * D_MODEL + lane * 8) = res;
}

// -------------------- MFMA GEMM 128x128 (proj only), BK=64, XCD swizzle --------------
__global__ __launch_bounds__(256) void mfma_gemm(const short* __restrict__ A,
                                                 const short* __restrict__ WT,
                                                 const float* bias,
                                                 float* __restrict__ C,
                                                 int M, int N, int K) {
    __shared__ __align__(16) short As[128][72];
    __shared__ __align__(16) short Bs[128][72];
    int tid = threadIdx.x;
    int lane = tid & 63, wid = tid >> 6;
    int wm = wid >> 1, wn = wid & 1;
    int gx = gridDim.x;
    int bid = blockIdx.y * gx + blockIdx.x;
    int per = (gx * gridDim.y) >> 3;
    int nb = (bid & 7) * per + (bid >> 3);
    int brow = (nb % gx) * 128;
    int bcol = (nb / gx) * 128;
    int l15 = lane & 15, lk = lane >> 4;

    f32x4 acc[4][4] = {};

    for (int k0 = 0; k0 < K; k0 += 64) {
        // stage 128x64 per matrix: 1024 chunks of 8 shorts, 4 per thread
#pragma unroll
        for (int j = 0; j < 4; ++j) {
            int c = tid + 256 * j;
            int r = c >> 3, seg = (c & 7) * 8;
            *(bf16x8*)&As[r][seg] = *(const bf16x8*)(A  + (size_t)(brow + r) * K + k0 + seg);
            *(bf16x8*)&Bs[r][seg] = *(const bf16x8*)(WT + (size_t)(bcol + r) * K + k0 + seg);
        }
        __syncthreads();
#pragma unroll
        for (int ks = 0; ks < 2; ++ks) {
            bf16x8 af[4], bfv[4];
#pragma unroll
            for (int mf = 0; mf < 4; ++mf)
                af[mf] = *(const bf16x8*)&As[64 * wm + 16 * mf + l15][32 * ks + 8 * lk];
#pragma unroll
            for (int nf = 0; nf < 4; ++nf)
                bfv[nf] = *(const bf16x8*)&Bs[64 * wn + 16 * nf + l15][32 * ks + 8 * lk];
            __builtin_amdgcn_s_setprio(1);
#pragma unroll
            for (int mf = 0; mf < 4; ++mf)
#pragma unroll
                for (int nf = 0; nf < 4; ++nf)
                    acc[mf][nf] = __builtin_amdgcn_mfma_f32_16x16x32_bf16(af[mf], bfv[nf], acc[mf][nf], 0, 0, 0);
            __builtin_amdgcn_s_setprio(0);
        }
        __syncthreads();
    }

#pragma unroll
    for (int mf = 0; mf < 4; ++mf) {
#pragma unroll
        for (int nf = 0; nf < 4; ++nf) {
            int n = bcol + 64 * wn + 16 * nf + l15;
            float bv = bias ? bias[n] : 0.0f;
#pragma unroll
            for (int reg = 0; reg < 4; ++reg) {
                int m = brow + 64 * wm + 16 * mf + lk * 4 + reg;
                __builtin_nontemporal_store(acc[mf][nf][reg] + bv, C + (size_t)m * N + n);
            }
        }
    }
}

// -------------------- MFMA GEMM 64x64, BK=128, WT [N][K], XCD swizzle ----------------
// ATOMIC=0: normal epilogue (bias/resid/relu, optional V-transpose split via vt/vcol0).
// ATOMIC=1: split-K over gridDim.z; atomicAdd into f32 C (holds residual); bias z==0.
template <typename OutT, int ATOMIC>
__global__ __launch_bounds__(256) void mfma_gemm64(const short* __restrict__ A,
                                                   const short* __restrict__ WT,
                                                   const float* bias, const float* resid,
                                                   OutT* __restrict__ C,
                                                   short* __restrict__ vt, int vcol0,
                                                   int M, int N, int K, int relu) {
    __shared__ __align__(16) short As[64][136];
    __shared__ __align__(16) short Bs[64][136];
    int tid = threadIdx.x;
    int lane = tid & 63, wid = tid >> 6;
    int wm = wid >> 1, wn = wid & 1;
    int gx = gridDim.x, gy = gridDim.y;
    int bid = blockIdx.y * gx + blockIdx.x;
    int per = (gx * gy) >> 3;
    int nb = (bid & 7) * per + (bid >> 3);
    int brow = (nb % gy) * 64;
    int bcol = (nb / gy) * 64;
    int l15 = lane & 15, lk = lane >> 4;

    int kz = ATOMIC ? blockIdx.z : 0;
    int kper = ATOMIC ? (K / gridDim.z) : K;
    int kbeg = kz * kper, kend = kbeg + kper;

    f32x4 acc[2][2] = {};

    int ra = tid >> 2, sa = (tid & 3) * 32;

    for (int k0 = kbeg; k0 < kend; k0 += 128) {
        {
            const short* ab = A + (size_t)(brow + ra) * K + k0 + sa;
            const short* wb = WT + (size_t)(bcol + ra) * K + k0 + sa;
#pragma unroll
            for (int j = 0; j < 4; ++j) {
                *(bf16x8*)&As[ra][sa + 8 * j] = *(const bf16x8*)(ab + 8 * j);
                *(bf16x8*)&Bs[ra][sa + 8 * j] = *(const bf16x8*)(wb + 8 * j);
            }
        }
        __syncthreads();
        __builtin_amdgcn_s_setprio(1);
#pragma unroll
        for (int ks = 0; ks < 4; ++ks) {
            bf16x8 a0 = *(const bf16x8*)&As[32 * wm + l15][32 * ks + 8 * lk];
            bf16x8 a1 = *(const bf16x8*)&As[32 * wm + 16 + l15][32 * ks + 8 * lk];
            bf16x8 b0 = *(const bf16x8*)&Bs[32 * wn + l15][32 * ks + 8 * lk];
            bf16x8 b1 = *(const bf16x8*)&Bs[32 * wn + 16 + l15][32 * ks + 8 * lk];
            acc[0][0] = __builtin_amdgcn_mfma_f32_16x16x32_bf16(a0, b0, acc[0][0], 0, 0, 0);
            acc[0][1] = __builtin_amdgcn_mfma_f32_16x16x32_bf16(a0, b1, acc[0][1], 0, 0, 0);
            acc[1][0] = __builtin_amdgcn_mfma_f32_16x16x32_bf16(a1, b0, acc[1][0], 0, 0, 0);
            acc[1][1] = __builtin_amdgcn_mfma_f32_16x16x32_bf16(a1, b1, acc[1][1], 0, 0, 0);
        }
        __builtin_amdgcn_s_setprio(0);
        __syncthreads();
    }

    if constexpr (ATOMIC) {
        float* Cf = (float*)C;
#pragma unroll
        for (int mf = 0; mf < 2; ++mf) {
#pragma unroll
            for (int nf = 0; nf < 2; ++nf) {
                int n = bcol + 32 * wn + 16 * nf + l15;
                float bv = (kz == 0 && bias) ? bias[n] : 0.0f;
#pragma unroll
                for (int reg = 0; reg < 4; ++reg) {
                    int m = brow + 32 * wm + 16 * mf + lk * 4 + reg;
                    atomicAdd(Cf + (size_t)m * N + n, acc[mf][nf][reg] + bv);
                }
            }
        }
        return;
    }

    if (vt && bcol >= vcol0) {
        // transposed V store: token -> k, col -> (h, d)
#pragma unroll
        for (int mf = 0; mf < 2; ++mf) {
#pragma unroll
            for (int nf = 0; nf < 2; ++nf) {
                int rel = bcol + 32 * wn + 16 * nf + l15 - vcol0;
                int hh = rel >> 6, dd = rel & 63;
                int m0 = brow + 32 * wm + 16 * mf + 4 * lk;
                int b = m0 >> 10, k = m0 & 1023;
                short4 o4 = make_short4(f2b(acc[mf][nf][0]), f2b(acc[mf][nf][1]),
                                        f2b(acc[mf][nf][2]), f2b(acc[mf][nf][3]));
                *(short4*)(vt + (((size_t)b * N_HEADS + hh) * HEAD + dd) * SEQ + k) = o4;
            }
        }
        return;
    }

#pragma unroll
    for (int mf = 0; mf < 2; ++mf) {
#pragma unroll
        for (int nf = 0; nf < 2; ++nf) {
            int n = bcol + 32 * wn + 16 * nf + l15;
            float bv = bias ? bias[n] : 0.0f;
#pragma unroll
            for (int reg = 0; reg < 4; ++reg) {
                int m = brow + 32 * wm + 16 * mf + lk * 4 + reg;
                float v = acc[mf][nf][reg] + bv;
                if (resid) v += resid[(size_t)m * N + n];
                if (relu)  v = fmaxf(v, 0.0f);
                storev(C + (size_t)m * N + n, v);
            }
        }
    }
}

// -------------------- MFMA flash attention: 4 waves = 2 q-subtiles x 2 k-halves ------
__global__ __launch_bounds__(256) void fattn_kernel(const short* __restrict__ Q, int strq,
                                                    const short* __restrict__ Kp, int strkv,
                                                    const short* __restrict__ Vtg,
                                                    short* __restrict__ out, int causal) {
    __shared__ __align__(16) short smem[23040];   // Ks[2][64][72] Vs[2][64][72] Ps[2][32][72]
    short* KsB = smem;
    short* VsB = smem + 9216;
    short* PsB = smem + 18432;
    float* red = (float*)smem;                    // aliases Ks region after main loop

    int tid = threadIdx.x;
    int lane = tid & 63, w = tid >> 6;
    int l15 = lane & 15, lk = lane >> 4;
    int qsub = w & 1, khalf = w >> 1;
    int t127 = tid & 127;
    int qt = blockIdx.x, h = blockIdx.y, bb = blockIdx.z;
    int q0 = qt * 32;

    short* Ks = KsB + khalf * 4608;
    short* Vs = VsB + khalf * 4608;
    short* Ps = PsB + khalf * 2304;

    bf16x8 qf[2];
    {
        const short* qbase = Q + ((size_t)(bb * SEQ + q0 + 16 * qsub + l15)) * strq + h * HEAD;
        qf[0] = *(const bf16x8*)(qbase + 8 * lk);
        qf[1] = *(const bf16x8*)(qbase + 32 + 8 * lk);
    }

    f32x4 o[4] = {};
    float lsum = 0.0f;

    int nkt = causal ? ((q0 + 31) / 64 + 1) : (SEQ / 64);
    int half0 = (nkt + 1) >> 1, half1 = nkt - half0;

    int rr = t127 >> 1, sg = (t127 & 1) * 32;
    int qg = q0 + 16 * qsub + l15;

    const short* vbase = Vtg + (((size_t)bb * N_HEADS + h) * HEAD + rr) * SEQ;

    for (int t = 0; t < half0; ++t) {
        int myTile = khalf ? (half0 + t) : t;
        bool active = khalf ? (t < half1) : true;
        int k0 = myTile * 64;
        __syncthreads();
        if (active) {
            const short* ksrc = Kp + ((size_t)(bb * SEQ + k0 + rr)) * strkv + h * HEAD + sg;
            const short* vsrc = vbase + k0 + sg;
#pragma unroll
            for (int j = 0; j < 4; ++j) {
                *(bf16x8*)&Ks[rr * 72 + sg + 8 * j] = *(const bf16x8*)(ksrc + 8 * j);
                *(bf16x8*)&Vs[rr * 72 + sg + 8 * j] = *(const bf16x8*)(vsrc + 8 * j);
            }
        }
        __syncthreads();
        if (!active) continue;

        f32x4 s[4] = {};
        __builtin_amdgcn_s_setprio(1);
#pragma unroll
        for (int kf = 0; kf < 4; ++kf) {
            bf16x8 k0f = *(const bf16x8*)&Ks[(16 * kf + l15) * 72 + 8 * lk];
            bf16x8 k1f = *(const bf16x8*)&Ks[(16 * kf + l15) * 72 + 32 + 8 * lk];
            s[kf] = __builtin_amdgcn_mfma_f32_16x16x32_bf16(k0f, qf[0], s[kf], 0, 0, 0);
            s[kf] = __builtin_amdgcn_mfma_f32_16x16x32_bf16(k1f, qf[1], s[kf], 0, 0, 0);
        }
        __builtin_amdgcn_s_setprio(0);

        bool diag = causal && (myTile == nkt - 1);
        float psum = 0.0f;
#pragma unroll
        for (int kf = 0; kf < 4; ++kf) {
            short4 pq;
#pragma unroll
            for (int r = 0; r < 4; ++r) {
                float sv = s[kf][r] * 0.125f;
                if (diag && (k0 + 16 * kf + 4 * lk + r > qg)) sv = -1e30f;
                float p = __expf(sv);
                psum += p;
                ((short*)&pq)[r] = f2b(p);
            }
            *(short4*)&Ps[(16 * qsub + l15) * 72 + 16 * kf + 4 * lk] = pq;
        }
        psum += __shfl_xor(psum, 16);
        psum += __shfl_xor(psum, 32);
        lsum += psum;

        __builtin_amdgcn_s_setprio(1);
#pragma unroll
        for (int ks = 0; ks < 2; ++ks) {
            bf16x8 pb = *(const bf16x8*)&Ps[(16 * qsub + l15) * 72 + 32 * ks + 8 * lk];
#pragma unroll
            for (int df = 0; df < 4; ++df) {
                bf16x8 vf = *(const bf16x8*)&Vs[(16 * df + l15) * 72 + 32 * ks + 8 * lk];
                o[df] = __builtin_amdgcn_mfma_f32_16x16x32_bf16(vf, pb, o[df], 0, 0, 0);
            }
        }
        __builtin_amdgcn_s_setprio(0);
    }

    __syncthreads();
    {
        int base = (w * 64 + lane) * 17;
#pragma unroll
        for (int df = 0; df < 4; ++df)
#pragma unroll
            for (int r = 0; r < 4; ++r) red[base + df * 4 + r] = o[df][r];
        red[base + 16] = lsum;
    }
    __syncthreads();
    if (khalf == 0) {
        int pbase = ((w + 2) * 64 + lane) * 17;
        float inv = 1.0f / (lsum + red[pbase + 16]);
        short* orow = out + ((size_t)(bb * SEQ + qg)) * D_MODEL + h * HEAD;
#pragma unroll
        for (int df = 0; df < 4; ++df) {
            short4 o4 = make_short4(f2b((o[df][0] + red[pbase + df * 4 + 0]) * inv),
                                    f2b((o[df][1] + red[pbase + df * 4 + 1]) * inv),
                                    f2b((o[df][2] + red[pbase + df * 4 + 2]) * inv),
                                    f2b((o[df][3] + red[pbase + df * 4 + 3]) * inv));
            *(short4*)(orow + 16 * df + 4 * lk) = o4;
        }
    }
}

// -------------------- orchestration --------------------
extern "C" void kernel_launch(void* const* d_in, const int* in_sizes, int n_in,
                              void* d_out, int out_size, void* d_ws, size_t ws_size,
                              hipStream_t stream) {
    const int*   src       = (const int*)  d_in[0];
    const int*   tgt       = (const int*)  d_in[1];
    const float* src_emb   = (const float*)d_in[4];
    const float* tgt_emb   = (const float*)d_in[5];
    const float* enc_att_w = (const float*)d_in[6];
    const float* enc_ff_w1 = (const float*)d_in[7];
    const float* enc_ff_b1 = (const float*)d_in[8];
    const float* enc_ff_w2 = (const float*)d_in[9];
    const float* enc_ff_b2 = (const float*)d_in[10];
    const float* enc_norm_g= (const float*)d_in[11];
    const float* enc_norm_b= (const float*)d_in[12];
    const float* enc_fin_g = (const float*)d_in[13];
    const float* enc_fin_b = (const float*)d_in[14];
    const float* dec_att_w = (const float*)d_in[15];
    const float* dec_ff_w1 = (const float*)d_in[16];
    const float* dec_ff_b1 = (const float*)d_in[17];
    const float* dec_ff_w2 = (const float*)d_in[18];
    const float* dec_ff_b2 = (const float*)d_in[19];
    const float* dec_norm_g= (const float*)d_in[20];
    const float* dec_norm_b= (const float*)d_in[21];
    const float* dec_fin_g = (const float*)d_in[22];
    const float* dec_fin_b = (const float*)d_in[23];
    const float* proj_w    = (const float*)d_in[24];
    const float* proj_b    = (const float*)d_in[25];
    float* out = (float*)d_out;

    const int NROW = BATCH * SEQ;
    const size_t CH = (size_t)NROW * D_MODEL;
    float* ws = (float*)d_ws;
    float* x = ws;                 // enc residual (f32)
    float* y = x + CH;             // dec residual (f32)
    short* z    = (short*)(y + CH);
    short* qkv  = z + CH;          // stride-1536 Q,K ; cross: [0..CH)=crossq, [CH..3CH)=kv
    short* ab   = qkv + 3 * CH;
    short* encb = ab + CH;
    short* ff   = encb + CH;       // 4*CH
    short* vt   = ff + 4 * CH;     // V transposed [B][H][HEAD][SEQ]
    short* wts  = vt + CH;

    short* w_enc_qkv = wts;                         // 4 x [1536][512] (W^T)
    short* w_dec_qkv = w_enc_qkv + 4 * 786432;
    short* w_dec_kv  = w_dec_qkv + 4 * 786432;      // 4 x [1024][512]
    short* w_o       = w_dec_kv  + 4 * 524288;      // 16 x [512][512]
    short* w_enc_ff1 = w_o       + 16 * 262144;
    short* w_enc_ff2 = w_enc_ff1 + 4194304;
    short* w_dec_ff1 = w_enc_ff2 + 4194304;
    short* w_dec_ff2 = w_dec_ff1 + 4194304;
    short* w_proj    = w_dec_ff2 + 4194304;         // [32000][512]

    // ---- weight transpose+convert ----
    {
        dim3 ga(64, 48);
        repack_attT_kernel<<<ga, 256, 0, stream>>>(enc_att_w, dec_att_w,
                                                   w_enc_qkv, w_dec_qkv, w_dec_kv, w_o);
        dim3 gf1(D_FF / 64, D_MODEL / 64, 4);
        transT_kernel<<<gf1, 256, 0, stream>>>(enc_ff_w1, w_enc_ff1, D_MODEL, D_FF);
        transT_kernel<<<gf1, 256, 0, stream>>>(dec_ff_w1, w_dec_ff1, D_MODEL, D_FF);
        dim3 gf2(D_MODEL / 64, D_FF / 64, 4);
        transT_kernel<<<gf2, 256, 0, stream>>>(enc_ff_w2, w_enc_ff2, D_FF, D_MODEL);
        transT_kernel<<<gf2, 256, 0, stream>>>(dec_ff_w2, w_dec_ff2, D_FF, D_MODEL);
        dim3 gp(VOCAB / 64, D_MODEL / 64);
        transT_kernel<<<gp, 256, 0, stream>>>(proj_w, w_proj, D_MODEL, VOCAB);
    }

    auto g64_b = [&](const short* A, const short* W, const float* bias, const float* resid,
                     short* C, short* vto, int vcol0, int M, int N, int K, int relu) {
        dim3 g(N / 64, M / 64);
        mfma_gemm64<short, 0><<<g, 256, 0, stream>>>(A, W, bias, resid, C, vto, vcol0, M, N, K, relu);
    };
    // split-K atomic accumulate into f32 C (C already holds the residual)
    auto g64_atomic = [&](const short* A, const short* W, const float* bias,
                          float* C, int M, int N, int K, int split) {
        dim3 g(N / 64, M / 64, split);
        mfma_gemm64<float, 1><<<g, 256, 0, stream>>>(A, W, bias, nullptr, C, nullptr, 0, M, N, K, 0);
    };
    auto ln = [&](const float* in, const float* g, const float* b, short* outp) {
        ln_kernel<<<NROW / 4, 256, 0, stream>>>(in, g, b, outp);
    };
    auto attn = [&](const short* Q, int strq, const short* K, int strkv, short* O, int causal) {
        dim3 g(SEQ / 32, N_HEADS, BATCH);
        fattn_kernel<<<g, 256, 0, stream>>>(Q, strq, K, strkv, vt, O, causal);
    };

    // ---------------- embed both streams ----------------
    {
        dim3 ge(NROW, 2);
        embed_kernel<<<ge, 256, 0, stream>>>(src, tgt, src_emb, tgt_emb, x, y);
    }

    // ---------------- encoder ----------------
    for (int i = 0; i < N_LAYERS; ++i) {
        ln(x, enc_norm_g + (i * 2 + 0) * D_MODEL, enc_norm_b + (i * 2 + 0) * D_MODEL, z);
        g64_b(z, w_enc_qkv + (size_t)i * 786432, nullptr, nullptr, qkv, vt, 1024, NROW, 1536, D_MODEL, 0);
        attn(qkv, 1536, qkv + 512, 1536, ab, 0);
        g64_atomic(ab, w_o + (size_t)i * 262144, nullptr, x, NROW, D_MODEL, D_MODEL, 4);
        ln(x, enc_norm_g + (i * 2 + 1) * D_MODEL, enc_norm_b + (i * 2 + 1) * D_MODEL, z);
        g64_b(z, w_enc_ff1 + (size_t)i * 1048576, enc_ff_b1 + i * D_FF, nullptr, ff, nullptr, 0, NROW, D_FF, D_MODEL, 1);
        g64_atomic(ff, w_enc_ff2 + (size_t)i * 1048576, enc_ff_b2 + i * D_MODEL, x, NROW, D_MODEL, D_FF, 8);
    }
    ln(x, enc_fin_g, enc_fin_b, encb);

    // ---------------- decoder ----------------
    for (int i = 0; i < N_LAYERS; ++i) {
        // self-attention (causal)
        ln(y, dec_norm_g + (i * 3 + 0) * D_MODEL, dec_norm_b + (i * 3 + 0) * D_MODEL, z);
        g64_b(z, w_dec_qkv + (size_t)i * 786432, nullptr, nullptr, qkv, vt, 1024, NROW, 1536, D_MODEL, 0);
        attn(qkv, 1536, qkv + 512, 1536, ab, 1);
        g64_atomic(ab, w_o + (size_t)(4 + i) * 262144, nullptr, y, NROW, D_MODEL, D_MODEL, 4);
        // cross-attention
        {
            short* crossq = qkv;
            short* kv     = qkv + CH;
            ln(y, dec_norm_g + (i * 3 + 1) * D_MODEL, dec_norm_b + (i * 3 + 1) * D_MODEL, z);
            g64_b(z, w_o + (size_t)(8 + i) * 262144, nullptr, nullptr, crossq, nullptr, 0, NROW, D_MODEL, D_MODEL, 0);
            g64_b(encb, w_dec_kv + (size_t)i * 524288, nullptr, nullptr, kv, vt, 512, NROW, 1024, D_MODEL, 0);
            attn(crossq, 512, kv, 1024, ab, 0);
        }
        g64_atomic(ab, w_o + (size_t)(12 + i) * 262144, nullptr, y, NROW, D_MODEL, D_MODEL, 4);
        // feed-forward
        ln(y, dec_norm_g + (i * 3 + 2) * D_MODEL, dec_norm_b + (i * 3 + 2) * D_MODEL, z);
        g64_b(z, w_dec_ff1 + (size_t)i * 1048576, dec_ff_b1 + i * D_FF, nullptr, ff, nullptr, 0, NROW, D_FF, D_MODEL, 1);
        g64_atomic(ff, w_dec_ff2 + (size_t)i * 1048576, dec_ff_b2 + i * D_MODEL, y, NROW, D_MODEL, D_FF, 8);
    }
    ln(y, dec_fin_g, dec_fin_b, z);

    // ---------------- final projection -> f32 logits ----------------
    dim3 pg(NROW / 128, VOCAB / 128);
    mfma_gemm<<<pg, 256, 0, stream>>>(z, w_proj, proj_b, out, NROW, VOCAB, D_MODEL);
}

// Round 19
// 1030.913 us; speedup vs baseline: 1.1487x; 1.1487x over previous
//
#include <hip/hip_runtime.h>
#include <hip/hip_bf16.h>
#include <math.h>

#define D_MODEL 512
#define N_HEADS 8
#define HEAD 64
#define D_FF   2048
#define N_LAYERS 4
#define VOCAB  32000
#define BATCH  2
#define SEQ    1024

typedef __attribute__((ext_vector_type(8))) short bf16x8;
typedef __attribute__((ext_vector_type(4))) float f32x4;

__device__ __forceinline__ float b2f(short s) {
    unsigned int u = ((unsigned int)(unsigned short)s) << 16;
    float f; __builtin_memcpy(&f, &u, 4);
    return f;
}
__device__ __forceinline__ short f2b(float f) {
    __hip_bfloat16 h = __float2bfloat16(f);
    unsigned short u; __builtin_memcpy(&u, &h, 2);
    return (short)u;
}
__device__ __forceinline__ void storev(float* p, float v) { *p = v; }
__device__ __forceinline__ void storev(short* p, float v) { *p = f2b(v); }

// -------------------- tiled transpose+convert: src f32 [K][N] -> dst bf16 [N][K] -----
__device__ __forceinline__ void transT_tile(const float* __restrict__ s,
                                            short* __restrict__ d,
                                            int K, int N, int tx, int ty, int tid) {
    __shared__ float t[64][65];
    int r = tid >> 2, c4 = (tid & 3) * 4;
#pragma unroll
    for (int jj = 0; jj < 4; ++jj) {
        int col = c4 + jj * 16;
        *(float4*)&t[r][col] = *(const float4*)(s + (size_t)(ty * 64 + r) * N + tx * 64 + col);
    }
    __syncthreads();
#pragma unroll
    for (int jj = 0; jj < 4; ++jj) {
        int kc = c4 + jj * 16;
        short4 o = make_short4(f2b(t[kc][r]), f2b(t[kc + 1][r]),
                               f2b(t[kc + 2][r]), f2b(t[kc + 3][r]));
        *(short4*)(d + (size_t)(tx * 64 + r) * K + ty * 64 + kc) = o;
    }
}

__global__ __launch_bounds__(256) void transT_kernel(const float* __restrict__ src,
                                                     short* __restrict__ dst,
                                                     int K, int N) {
    const float* s = src + (size_t)blockIdx.z * K * N;
    short* d = dst + (size_t)blockIdx.z * K * N;
    transT_tile(s, d, K, N, blockIdx.x, blockIdx.y, threadIdx.x);
}

__global__ __launch_bounds__(256) void repack_attT_kernel(const float* __restrict__ encw,
                                                          const float* __restrict__ decw,
                                                          short* __restrict__ w_enc_qkv,
                                                          short* __restrict__ w_dec_qkv,
                                                          short* __restrict__ w_dec_kv,
                                                          short* __restrict__ w_o) {
    int z = blockIdx.y;
    const float* s; short* d;
    if (z < 12)      { int i = z / 3, j = z % 3;
                       s = encw + (size_t)(i * 4 + j) * 262144;
                       d = w_enc_qkv + (size_t)i * 786432 + j * 262144; }
    else if (z < 24) { int u = z - 12, i = u / 3, j = u % 3;
                       s = decw + (size_t)(i * 8 + j) * 262144;
                       d = w_dec_qkv + (size_t)i * 786432 + j * 262144; }
    else if (z < 32) { int u = z - 24, i = u / 2, j = u % 2;
                       s = decw + (size_t)(i * 8 + 5 + j) * 262144;
                       d = w_dec_kv + (size_t)i * 524288 + j * 262144; }
    else             { int u = z - 32; const float* b; int mi;
                       if (u < 4)       { b = encw; mi = u * 4 + 3; }
                       else if (u < 8)  { b = decw; mi = (u - 4) * 8 + 3; }
                       else if (u < 12) { b = decw; mi = (u - 8) * 8 + 4; }
                       else             { b = decw; mi = (u - 12) * 8 + 7; }
                       s = b + (size_t)mi * 262144; d = w_o + (size_t)u * 262144; }
    int bx = blockIdx.x;
    transT_tile(s, d, 512, 512, bx & 7, bx >> 3, threadIdx.x);
}

// -------------------- embedding + posenc, both streams in one launch ----------------
__global__ void embed_kernel(const int* __restrict__ tokA, const int* __restrict__ tokB,
                             const float* __restrict__ embA, const float* __restrict__ embB,
                             float* __restrict__ outA, float* __restrict__ outB) {
    int row = blockIdx.x;
    const int* tok = blockIdx.y ? tokB : tokA;
    const float* emb = blockIdx.y ? embB : embA;
    float* out = blockIdx.y ? outB : outA;
    int s = row % SEQ;
    int token = tok[row];
    const float scale = 22.627416997969522f;
    const float c = -1.7988945941359737e-2f;
    for (int d = threadIdx.x; d < D_MODEL; d += blockDim.x) {
        int i2 = (d >> 1) * 2;
        float div = expf((float)i2 * c);
        float ang = (float)s * div;
        float pe = (d & 1) ? cosf(ang) : sinf(ang);
        out[(size_t)row * D_MODEL + d] = emb[(size_t)token * D_MODEL + d] * scale + pe;
    }
}

// -------------------- layernorm: wave-per-row, 4 rows/block --------------------
__global__ __launch_bounds__(256) void ln_kernel(const float* __restrict__ x,
                                                 const float* __restrict__ g,
                                                 const float* __restrict__ b,
                                                 short* __restrict__ out) {
    int row = blockIdx.x * 4 + (threadIdx.x >> 6);
    int lane = threadIdx.x & 63;
    const float4* xr = (const float4*)(x + (size_t)row * D_MODEL);
    float4 v0 = xr[lane * 2], v1 = xr[lane * 2 + 1];
    float c[8] = { v0.x, v0.y, v0.z, v0.w, v1.x, v1.y, v1.z, v1.w };
    float s = ((c[0] + c[1]) + (c[2] + c[3])) + ((c[4] + c[5]) + (c[6] + c[7]));
#pragma unroll
    for (int off = 1; off < 64; off <<= 1) s += __shfl_xor(s, off);
    float mean = s * (1.0f / 512.0f);
    float q = 0.0f;
#pragma unroll
    for (int j = 0; j < 8; ++j) { c[j] -= mean; q += c[j] * c[j]; }
#pragma unroll
    for (int off = 1; off < 64; off <<= 1) q += __shfl_xor(q, off);
    float inv = 1.0f / sqrtf(q * (1.0f / 511.0f) + 1e-6f);
    const float4* gp = (const float4*)g;
    const float4* bp = (const float4*)b;
    float4 g0 = gp[lane * 2], g1 = gp[lane * 2 + 1];
    float4 b0 = bp[lane * 2], b1 = bp[lane * 2 + 1];
    float gg[8] = { g0.x, g0.y, g0.z, g0.w, g1.x, g1.y, g1.z, g1.w };
    float bb[8] = { b0.x, b0.y, b0.z, b0.w, b1.x, b1.y, b1.z, b1.w };
    bf16x8 res;
#pragma unroll
    for (int j = 0; j < 8; ++j) res[j] = f2b(gg[j] * (c[j] * inv) + bb[j]);
    *(bf16x8*)(out + (size_t)row * D_MODEL + lane * 8) = res;
}

// -------------------- MFMA GEMM 128x128 (proj only), BK=64, XCD swizzle --------------
__global__ __launch_bounds__(256) void mfma_gemm(const short* __restrict__ A,
                                                 const short* __restrict__ WT,
                                                 const float* bias,
                                                 float* __restrict__ C,
                                                 int M, int N, int K) {
    __shared__ __align__(16) short As[128][72];
    __shared__ __align__(16) short Bs[128][72];
    int tid = threadIdx.x;
    int lane = tid & 63, wid = tid >> 6;
    int wm = wid >> 1, wn = wid & 1;
    int gx = gridDim.x;
    int bid = blockIdx.y * gx + blockIdx.x;
    int per = (gx * gridDim.y) >> 3;
    int nb = (bid & 7) * per + (bid >> 3);
    int brow = (nb % gx) * 128;
    int bcol = (nb / gx) * 128;
    int l15 = lane & 15, lk = lane >> 4;

    f32x4 acc[4][4] = {};

    for (int k0 = 0; k0 < K; k0 += 64) {
#pragma unroll
        for (int j = 0; j < 4; ++j) {
            int c = tid + 256 * j;
            int r = c >> 3, seg = (c & 7) * 8;
            *(bf16x8*)&As[r][seg] = *(const bf16x8*)(A  + (size_t)(brow + r) * K + k0 + seg);
            *(bf16x8*)&Bs[r][seg] = *(const bf16x8*)(WT + (size_t)(bcol + r) * K + k0 + seg);
        }
        __syncthreads();
#pragma unroll
        for (int ks = 0; ks < 2; ++ks) {
            bf16x8 af[4], bfv[4];
#pragma unroll
            for (int mf = 0; mf < 4; ++mf)
                af[mf] = *(const bf16x8*)&As[64 * wm + 16 * mf + l15][32 * ks + 8 * lk];
#pragma unroll
            for (int nf = 0; nf < 4; ++nf)
                bfv[nf] = *(const bf16x8*)&Bs[64 * wn + 16 * nf + l15][32 * ks + 8 * lk];
            __builtin_amdgcn_s_setprio(1);
#pragma unroll
            for (int mf = 0; mf < 4; ++mf)
#pragma unroll
                for (int nf = 0; nf < 4; ++nf)
                    acc[mf][nf] = __builtin_amdgcn_mfma_f32_16x16x32_bf16(af[mf], bfv[nf], acc[mf][nf], 0, 0, 0);
            __builtin_amdgcn_s_setprio(0);
        }
        __syncthreads();
    }

#pragma unroll
    for (int mf = 0; mf < 4; ++mf) {
#pragma unroll
        for (int nf = 0; nf < 4; ++nf) {
            int n = bcol + 64 * wn + 16 * nf + l15;
            float bv = bias ? bias[n] : 0.0f;
#pragma unroll
            for (int reg = 0; reg < 4; ++reg) {
                int m = brow + 64 * wm + 16 * mf + lk * 4 + reg;
                __builtin_nontemporal_store(acc[mf][nf][reg] + bv, C + (size_t)m * N + n);
            }
        }
    }
}

// -------------------- MFMA GEMM 64x64, BK=128, WT [N][K], XCD swizzle ----------------
// ATOMIC=0: normal epilogue (bias/resid/relu, optional V-transpose split via vt/vcol0).
// ATOMIC=1: split-K over gridDim.z; atomicAdd into f32 C (holds residual); bias z==0.
template <typename OutT, int ATOMIC>
__global__ __launch_bounds__(256) void mfma_gemm64(const short* __restrict__ A,
                                                   const short* __restrict__ WT,
                                                   const float* bias, const float* resid,
                                                   OutT* __restrict__ C,
                                                   short* __restrict__ vt, int vcol0,
                                                   int M, int N, int K, int relu) {
    __shared__ __align__(16) short As[64][136];
    __shared__ __align__(16) short Bs[64][136];
    int tid = threadIdx.x;
    int lane = tid & 63, wid = tid >> 6;
    int wm = wid >> 1, wn = wid & 1;
    int gx = gridDim.x, gy = gridDim.y;
    int bid = blockIdx.y * gx + blockIdx.x;
    int per = (gx * gy) >> 3;
    int nb = (bid & 7) * per + (bid >> 3);
    int brow = (nb % gy) * 64;
    int bcol = (nb / gy) * 64;
    int l15 = lane & 15, lk = lane >> 4;

    int kz = ATOMIC ? blockIdx.z : 0;
    int kper = ATOMIC ? (K / gridDim.z) : K;
    int kbeg = kz * kper, kend = kbeg + kper;

    f32x4 acc[2][2] = {};

    int ra = tid >> 2, sa = (tid & 3) * 32;

    for (int k0 = kbeg; k0 < kend; k0 += 128) {
        {
            const short* ab = A + (size_t)(brow + ra) * K + k0 + sa;
            const short* wb = WT + (size_t)(bcol + ra) * K + k0 + sa;
#pragma unroll
            for (int j = 0; j < 4; ++j) {
                *(bf16x8*)&As[ra][sa + 8 * j] = *(const bf16x8*)(ab + 8 * j);
                *(bf16x8*)&Bs[ra][sa + 8 * j] = *(const bf16x8*)(wb + 8 * j);
            }
        }
        __syncthreads();
        __builtin_amdgcn_s_setprio(1);
#pragma unroll
        for (int ks = 0; ks < 4; ++ks) {
            bf16x8 a0 = *(const bf16x8*)&As[32 * wm + l15][32 * ks + 8 * lk];
            bf16x8 a1 = *(const bf16x8*)&As[32 * wm + 16 + l15][32 * ks + 8 * lk];
            bf16x8 b0 = *(const bf16x8*)&Bs[32 * wn + l15][32 * ks + 8 * lk];
            bf16x8 b1 = *(const bf16x8*)&Bs[32 * wn + 16 + l15][32 * ks + 8 * lk];
            acc[0][0] = __builtin_amdgcn_mfma_f32_16x16x32_bf16(a0, b0, acc[0][0], 0, 0, 0);
            acc[0][1] = __builtin_amdgcn_mfma_f32_16x16x32_bf16(a0, b1, acc[0][1], 0, 0, 0);
            acc[1][0] = __builtin_amdgcn_mfma_f32_16x16x32_bf16(a1, b0, acc[1][0], 0, 0, 0);
            acc[1][1] = __builtin_amdgcn_mfma_f32_16x16x32_bf16(a1, b1, acc[1][1], 0, 0, 0);
        }
        __builtin_amdgcn_s_setprio(0);
        __syncthreads();
    }

    if constexpr (ATOMIC) {
        float* Cf = (float*)C;
#pragma unroll
        for (int mf = 0; mf < 2; ++mf) {
#pragma unroll
            for (int nf = 0; nf < 2; ++nf) {
                int n = bcol + 32 * wn + 16 * nf + l15;
                float bv = (kz == 0 && bias) ? bias[n] : 0.0f;
#pragma unroll
                for (int reg = 0; reg < 4; ++reg) {
                    int m = brow + 32 * wm + 16 * mf + lk * 4 + reg;
                    atomicAdd(Cf + (size_t)m * N + n, acc[mf][nf][reg] + bv);
                }
            }
        }
        return;
    }

    if (vt && bcol >= vcol0) {
        // transposed V store: token -> k, col -> (h, d)
#pragma unroll
        for (int mf = 0; mf < 2; ++mf) {
#pragma unroll
            for (int nf = 0; nf < 2; ++nf) {
                int rel = bcol + 32 * wn + 16 * nf + l15 - vcol0;
                int hh = rel >> 6, dd = rel & 63;
                int m0 = brow + 32 * wm + 16 * mf + 4 * lk;
                int b = m0 >> 10, k = m0 & 1023;
                short4 o4 = make_short4(f2b(acc[mf][nf][0]), f2b(acc[mf][nf][1]),
                                        f2b(acc[mf][nf][2]), f2b(acc[mf][nf][3]));
                *(short4*)(vt + (((size_t)b * N_HEADS + hh) * HEAD + dd) * SEQ + k) = o4;
            }
        }
        return;
    }

#pragma unroll
    for (int mf = 0; mf < 2; ++mf) {
#pragma unroll
        for (int nf = 0; nf < 2; ++nf) {
            int n = bcol + 32 * wn + 16 * nf + l15;
            float bv = bias ? bias[n] : 0.0f;
#pragma unroll
            for (int reg = 0; reg < 4; ++reg) {
                int m = brow + 32 * wm + 16 * mf + lk * 4 + reg;
                float v = acc[mf][nf][reg] + bv;
                if (resid) v += resid[(size_t)m * N + n];
                if (relu)  v = fmaxf(v, 0.0f);
                storev(C + (size_t)m * N + n, v);
            }
        }
    }
}

// -------------------- MFMA flash attention: 4 waves = 2 q-subtiles x 2 k-halves ------
__global__ __launch_bounds__(256) void fattn_kernel(const short* __restrict__ Q, int strq,
                                                    const short* __restrict__ Kp, int strkv,
                                                    const short* __restrict__ Vtg,
                                                    short* __restrict__ out, int causal) {
    __shared__ __align__(16) short smem[23040];   // Ks[2][64][72] Vs[2][64][72] Ps[2][32][72]
    short* KsB = smem;
    short* VsB = smem + 9216;
    short* PsB = smem + 18432;
    float* red = (float*)smem;                    // aliases Ks region after main loop

    int tid = threadIdx.x;
    int lane = tid & 63, w = tid >> 6;
    int l15 = lane & 15, lk = lane >> 4;
    int qsub = w & 1, khalf = w >> 1;
    int t127 = tid & 127;
    int qt = blockIdx.x, h = blockIdx.y, bb = blockIdx.z;
    int q0 = qt * 32;

    short* Ks = KsB + khalf * 4608;
    short* Vs = VsB + khalf * 4608;
    short* Ps = PsB + khalf * 2304;

    bf16x8 qf[2];
    {
        const short* qbase = Q + ((size_t)(bb * SEQ + q0 + 16 * qsub + l15)) * strq + h * HEAD;
        qf[0] = *(const bf16x8*)(qbase + 8 * lk);
        qf[1] = *(const bf16x8*)(qbase + 32 + 8 * lk);
    }

    f32x4 o[4] = {};
    float lsum = 0.0f;

    int nkt = causal ? ((q0 + 31) / 64 + 1) : (SEQ / 64);
    int half0 = (nkt + 1) >> 1, half1 = nkt - half0;

    int rr = t127 >> 1, sg = (t127 & 1) * 32;
    int qg = q0 + 16 * qsub + l15;

    const short* vbase = Vtg + (((size_t)bb * N_HEADS + h) * HEAD + rr) * SEQ;

    for (int t = 0; t < half0; ++t) {
        int myTile = khalf ? (half0 + t) : t;
        bool active = khalf ? (t < half1) : true;
        int k0 = myTile * 64;
        __syncthreads();
        if (active) {
            const short* ksrc = Kp + ((size_t)(bb * SEQ + k0 + rr)) * strkv + h * HEAD + sg;
            const short* vsrc = vbase + k0 + sg;
#pragma unroll
            for (int j = 0; j < 4; ++j) {
                *(bf16x8*)&Ks[rr * 72 + sg + 8 * j] = *(const bf16x8*)(ksrc + 8 * j);
                *(bf16x8*)&Vs[rr * 72 + sg + 8 * j] = *(const bf16x8*)(vsrc + 8 * j);
            }
        }
        __syncthreads();
        if (!active) continue;

        f32x4 s[4] = {};
        __builtin_amdgcn_s_setprio(1);
#pragma unroll
        for (int kf = 0; kf < 4; ++kf) {
            bf16x8 k0f = *(const bf16x8*)&Ks[(16 * kf + l15) * 72 + 8 * lk];
            bf16x8 k1f = *(const bf16x8*)&Ks[(16 * kf + l15) * 72 + 32 + 8 * lk];
            s[kf] = __builtin_amdgcn_mfma_f32_16x16x32_bf16(k0f, qf[0], s[kf], 0, 0, 0);
            s[kf] = __builtin_amdgcn_mfma_f32_16x16x32_bf16(k1f, qf[1], s[kf], 0, 0, 0);
        }
        __builtin_amdgcn_s_setprio(0);

        bool diag = causal && (myTile == nkt - 1);
        float psum = 0.0f;
#pragma unroll
        for (int kf = 0; kf < 4; ++kf) {
            short4 pq;
#pragma unroll
            for (int r = 0; r < 4; ++r) {
                float sv = s[kf][r] * 0.125f;
                if (diag && (k0 + 16 * kf + 4 * lk + r > qg)) sv = -1e30f;
                float p = __expf(sv);
                psum += p;
                ((short*)&pq)[r] = f2b(p);
            }
            *(short4*)&Ps[(16 * qsub + l15) * 72 + 16 * kf + 4 * lk] = pq;
        }
        psum += __shfl_xor(psum, 16);
        psum += __shfl_xor(psum, 32);
        lsum += psum;

        __builtin_amdgcn_s_setprio(1);
#pragma unroll
        for (int ks = 0; ks < 2; ++ks) {
            bf16x8 pb = *(const bf16x8*)&Ps[(16 * qsub + l15) * 72 + 32 * ks + 8 * lk];
#pragma unroll
            for (int df = 0; df < 4; ++df) {
                bf16x8 vf = *(const bf16x8*)&Vs[(16 * df + l15) * 72 + 32 * ks + 8 * lk];
                o[df] = __builtin_amdgcn_mfma_f32_16x16x32_bf16(vf, pb, o[df], 0, 0, 0);
            }
        }
        __builtin_amdgcn_s_setprio(0);
    }

    __syncthreads();
    {
        int base = (w * 64 + lane) * 17;
#pragma unroll
        for (int df = 0; df < 4; ++df)
#pragma unroll
            for (int r = 0; r < 4; ++r) red[base + df * 4 + r] = o[df][r];
        red[base + 16] = lsum;
    }
    __syncthreads();
    if (khalf == 0) {
        int pbase = ((w + 2) * 64 + lane) * 17;
        float inv = 1.0f / (lsum + red[pbase + 16]);
        short* orow = out + ((size_t)(bb * SEQ + qg)) * D_MODEL + h * HEAD;
#pragma unroll
        for (int df = 0; df < 4; ++df) {
            short4 o4 = make_short4(f2b((o[df][0] + red[pbase + df * 4 + 0]) * inv),
                                    f2b((o[df][1] + red[pbase + df * 4 + 1]) * inv),
                                    f2b((o[df][2] + red[pbase + df * 4 + 2]) * inv),
                                    f2b((o[df][3] + red[pbase + df * 4 + 3]) * inv));
            *(short4*)(orow + 16 * df + 4 * lk) = o4;
        }
    }
}

// -------------------- orchestration --------------------
extern "C" void kernel_launch(void* const* d_in, const int* in_sizes, int n_in,
                              void* d_out, int out_size, void* d_ws, size_t ws_size,
                              hipStream_t stream) {
    const int*   src       = (const int*)  d_in[0];
    const int*   tgt       = (const int*)  d_in[1];
    const float* src_emb   = (const float*)d_in[4];
    const float* tgt_emb   = (const float*)d_in[5];
    const float* enc_att_w = (const float*)d_in[6];
    const float* enc_ff_w1 = (const float*)d_in[7];
    const float* enc_ff_b1 = (const float*)d_in[8];
    const float* enc_ff_w2 = (const float*)d_in[9];
    const float* enc_ff_b2 = (const float*)d_in[10];
    const float* enc_norm_g= (const float*)d_in[11];
    const float* enc_norm_b= (const float*)d_in[12];
    const float* enc_fin_g = (const float*)d_in[13];
    const float* enc_fin_b = (const float*)d_in[14];
    const float* dec_att_w = (const float*)d_in[15];
    const float* dec_ff_w1 = (const float*)d_in[16];
    const float* dec_ff_b1 = (const float*)d_in[17];
    const float* dec_ff_w2 = (const float*)d_in[18];
    const float* dec_ff_b2 = (const float*)d_in[19];
    const float* dec_norm_g= (const float*)d_in[20];
    const float* dec_norm_b= (const float*)d_in[21];
    const float* dec_fin_g = (const float*)d_in[22];
    const float* dec_fin_b = (const float*)d_in[23];
    const float* proj_w    = (const float*)d_in[24];
    const float* proj_b    = (const float*)d_in[25];
    float* out = (float*)d_out;

    const int NROW = BATCH * SEQ;
    const size_t CH = (size_t)NROW * D_MODEL;
    float* ws = (float*)d_ws;
    float* x = ws;                 // enc residual (f32)
    float* y = x + CH;             // dec residual (f32)
    short* z    = (short*)(y + CH);
    short* qkv  = z + CH;          // stride-1536 Q,K ; cross: [0..CH)=crossq, [CH..3CH)=kv
    short* ab   = qkv + 3 * CH;
    short* encb = ab + CH;
    short* ff   = encb + CH;       // 4*CH
    short* vt   = ff + 4 * CH;     // V transposed [B][H][HEAD][SEQ]
    short* wts  = vt + CH;

    short* w_enc_qkv = wts;                         // 4 x [1536][512] (W^T)
    short* w_dec_qkv = w_enc_qkv + 4 * 786432;
    short* w_dec_kv  = w_dec_qkv + 4 * 786432;      // 4 x [1024][512]
    short* w_o       = w_dec_kv  + 4 * 524288;      // 16 x [512][512]
    short* w_enc_ff1 = w_o       + 16 * 262144;
    short* w_enc_ff2 = w_enc_ff1 + 4194304;
    short* w_dec_ff1 = w_enc_ff2 + 4194304;
    short* w_dec_ff2 = w_dec_ff1 + 4194304;
    short* w_proj    = w_dec_ff2 + 4194304;         // [32000][512]

    // ---- weight transpose+convert ----
    {
        dim3 ga(64, 48);
        repack_attT_kernel<<<ga, 256, 0, stream>>>(enc_att_w, dec_att_w,
                                                   w_enc_qkv, w_dec_qkv, w_dec_kv, w_o);
        dim3 gf1(D_FF / 64, D_MODEL / 64, 4);
        transT_kernel<<<gf1, 256, 0, stream>>>(enc_ff_w1, w_enc_ff1, D_MODEL, D_FF);
        transT_kernel<<<gf1, 256, 0, stream>>>(dec_ff_w1, w_dec_ff1, D_MODEL, D_FF);
        dim3 gf2(D_MODEL / 64, D_FF / 64, 4);
        transT_kernel<<<gf2, 256, 0, stream>>>(enc_ff_w2, w_enc_ff2, D_FF, D_MODEL);
        transT_kernel<<<gf2, 256, 0, stream>>>(dec_ff_w2, w_dec_ff2, D_FF, D_MODEL);
        dim3 gp(VOCAB / 64, D_MODEL / 64);
        transT_kernel<<<gp, 256, 0, stream>>>(proj_w, w_proj, D_MODEL, VOCAB);
    }

    auto g64_b = [&](const short* A, const short* W, const float* bias, const float* resid,
                     short* C, short* vto, int vcol0, int M, int N, int K, int relu) {
        dim3 g(N / 64, M / 64);
        mfma_gemm64<short, 0><<<g, 256, 0, stream>>>(A, W, bias, resid, C, vto, vcol0, M, N, K, relu);
    };
    // split-K atomic accumulate into f32 C (C already holds the residual)
    auto g64_atomic = [&](const short* A, const short* W, const float* bias,
                          float* C, int M, int N, int K, int split) {
        dim3 g(N / 64, M / 64, split);
        mfma_gemm64<float, 1><<<g, 256, 0, stream>>>(A, W, bias, nullptr, C, nullptr, 0, M, N, K, 0);
    };
    auto ln = [&](const float* in, const float* g, const float* b, short* outp) {
        ln_kernel<<<NROW / 4, 256, 0, stream>>>(in, g, b, outp);
    };
    auto attn = [&](const short* Q, int strq, const short* K, int strkv, short* O, int causal) {
        dim3 g(SEQ / 32, N_HEADS, BATCH);
        fattn_kernel<<<g, 256, 0, stream>>>(Q, strq, K, strkv, vt, O, causal);
    };

    // ---------------- embed both streams ----------------
    {
        dim3 ge(NROW, 2);
        embed_kernel<<<ge, 256, 0, stream>>>(src, tgt, src_emb, tgt_emb, x, y);
    }

    // ---------------- encoder ----------------
    for (int i = 0; i < N_LAYERS; ++i) {
        ln(x, enc_norm_g + (i * 2 + 0) * D_MODEL, enc_norm_b + (i * 2 + 0) * D_MODEL, z);
        g64_b(z, w_enc_qkv + (size_t)i * 786432, nullptr, nullptr, qkv, vt, 1024, NROW, 1536, D_MODEL, 0);
        attn(qkv, 1536, qkv + 512, 1536, ab, 0);
        g64_atomic(ab, w_o + (size_t)i * 262144, nullptr, x, NROW, D_MODEL, D_MODEL, 2);
        ln(x, enc_norm_g + (i * 2 + 1) * D_MODEL, enc_norm_b + (i * 2 + 1) * D_MODEL, z);
        g64_b(z, w_enc_ff1 + (size_t)i * 1048576, enc_ff_b1 + i * D_FF, nullptr, ff, nullptr, 0, NROW, D_FF, D_MODEL, 1);
        g64_atomic(ff, w_enc_ff2 + (size_t)i * 1048576, enc_ff_b2 + i * D_MODEL, x, NROW, D_MODEL, D_FF, 4);
    }
    ln(x, enc_fin_g, enc_fin_b, encb);

    // ---------------- decoder ----------------
    for (int i = 0; i < N_LAYERS; ++i) {
        // self-attention (causal)
        ln(y, dec_norm_g + (i * 3 + 0) * D_MODEL, dec_norm_b + (i * 3 + 0) * D_MODEL, z);
        g64_b(z, w_dec_qkv + (size_t)i * 786432, nullptr, nullptr, qkv, vt, 1024, NROW, 1536, D_MODEL, 0);
        attn(qkv, 1536, qkv + 512, 1536, ab, 1);
        g64_atomic(ab, w_o + (size_t)(4 + i) * 262144, nullptr, y, NROW, D_MODEL, D_MODEL, 2);
        // cross-attention
        {
            short* crossq = qkv;
            short* kv     = qkv + CH;
            ln(y, dec_norm_g + (i * 3 + 1) * D_MODEL, dec_norm_b + (i * 3 + 1) * D_MODEL, z);
            g64_b(z, w_o + (size_t)(8 + i) * 262144, nullptr, nullptr, crossq, nullptr, 0, NROW, D_MODEL, D_MODEL, 0);
            g64_b(encb, w_dec_kv + (size_t)i * 524288, nullptr, nullptr, kv, vt, 512, NROW, 1024, D_MODEL, 0);
            attn(crossq, 512, kv, 1024, ab, 0);
        }
        g64_atomic(ab, w_o + (size_t)(12 + i) * 262144, nullptr, y, NROW, D_MODEL, D_MODEL, 2);
        // feed-forward
        ln(y, dec_norm_g + (i * 3 + 2) * D_MODEL, dec_norm_b + (i * 3 + 2) * D_MODEL, z);
        g64_b(z, w_dec_ff1 + (size_t)i * 1048576, dec_ff_b1 + i * D_FF, nullptr, ff, nullptr, 0, NROW, D_FF, D_MODEL, 1);
        g64_atomic(ff, w_dec_ff2 + (size_t)i * 1048576, dec_ff_b2 + i * D_MODEL, y, NROW, D_MODEL, D_FF, 4);
    }
    ln(y, dec_fin_g, dec_fin_b, z);

    // ---------------- final projection -> f32 logits ----------------
    dim3 pg(NROW / 128, VOCAB / 128);
    mfma_gemm<<<pg, 256, 0, stream>>>(z, w_proj, proj_b, out, NROW, VOCAB, D_MODEL);
}